// Round 2
// baseline (211.802 us; speedup 1.0000x reference)
//
#include <hip/hip_runtime.h>
#include <hip/hip_bf16.h>

#define NB 16
#define NL 8192
#define ND 256
#define KSPLIT 16
#define CHUNK (NL / KSPLIT)   // 512 rows per block
#define BK 64

#define WS_G_OFF 256          // floats; Z partial for (b,ks) at ws[b*16+ks]

typedef __bf16 bf16_t;
typedef __attribute__((ext_vector_type(4))) __bf16 bf16x4;
typedef __attribute__((ext_vector_type(8))) __bf16 bf16x8;
typedef __attribute__((ext_vector_type(4))) float floatx4;

// LDS: per col (0..255), 8 chunks of 8 bf16 (16B); physical chunk = kg ^ fsw(col).
__device__ __forceinline__ int fsw(int col) {
    return ((col >> 2) & 7) ^ ((col & 3) << 1);
}

// One block = 1024 threads = 16 waves, one (ks,b) chunk of 512 rows.
// Wave w computes row-tile w x col-tiles (w+j)&15, j=0..8 -> 144 slots
// (136 unique upper-tri + 8 d=8 pairs written once each side, no overlap).
// Pipelining: register ping-pong (issue next iter's loads BEFORE consuming
// current regs -> vmcnt never drains to 0) + LDS double-buffer (one barrier
// per BK-iteration instead of two).
__global__ __launch_bounds__(1024, 4) void k_gemm(const float* __restrict__ x,
                                                  float* __restrict__ ws,
                                                  float* __restrict__ gram) {
    const int ks = blockIdx.x, b = blockIdx.y;
    const int t = threadIdx.x;
    const int lane = t & 63;
    const int w = __builtin_amdgcn_readfirstlane(t >> 6);   // wave id 0..15
    const int quad = lane >> 4, m = lane & 15;
    const int g = w >> 1, h = w & 1;   // 8-row chunk id, half within chunk

    __shared__ bf16_t lds[2 * 256 * 64];   // 64 KB, two swizzled buffers

    const float* xb = x + (size_t)b * NL * ND;
    const int l0 = ks * CHUNK;

    floatx4 acc[9];
    #pragma unroll
    for (int j = 0; j < 9; ++j)
        #pragma unroll
        for (int r = 0; r < 4; ++r) acc[j][r] = 0.f;

    float e_acc = 0.f;
    float4 xvA[4], xvB[4];   // wave w stages rows kk+4w..+3; lane covers cols 4*lane..+3
    {
        const float* gp = xb + (size_t)(l0 + w * 4) * ND + lane * 4;
        #pragma unroll
        for (int j = 0; j < 4; ++j) xvA[j] = *(const float4*)(gp + (size_t)j * ND);
    }

    auto body = [&](float4 (&cur)[4], float4 (&nxt)[4], int kk, int lb) {
        // ---- 1. issue next iter's loads FIRST (keeps vmcnt queue non-empty) ----
        if (kk + BK < CHUNK) {
            const float* gp = xb + (size_t)(l0 + kk + BK + w * 4) * ND + lane * 4;
            #pragma unroll
            for (int j = 0; j < 4; ++j) nxt[j] = *(const float4*)(gp + (size_t)j * ND);
        }
        // ---- 2. norm butterfly + scale (consumes cur; waits only older loads) ----
        float ss[4];
        #pragma unroll
        for (int j = 0; j < 4; ++j)
            ss[j] = cur[j].x * cur[j].x + cur[j].y * cur[j].y
                  + cur[j].z * cur[j].z + cur[j].w * cur[j].w;
        #pragma unroll
        for (int off = 32; off; off >>= 1) {
            #pragma unroll
            for (int j = 0; j < 4; ++j) ss[j] += __shfl_xor(ss[j], off, 64);
        }
        float s[4];
        #pragma unroll
        for (int j = 0; j < 4; ++j) {
            s[j] = __expf(0.5f * sqrtf(ss[j]));   // sqrt of softmax numerator
            e_acc += s[j] * s[j];
        }
        bf16x4 p[4];
        #pragma unroll
        for (int j = 0; j < 4; ++j) {
            const float* vf = (const float*)&cur[j];
            #pragma unroll
            for (int c = 0; c < 4; ++c) p[c][j] = (bf16_t)(vf[c] * s[j]);
        }
        // ---- 3. swizzled LDS write into buffer lb (safe: last read 2 iters ago) ----
        bf16_t* L = lds + lb * (256 * 64);
        #pragma unroll
        for (int c = 0; c < 4; ++c) {
            const int col = 4 * lane + c;
            *(bf16x4*)(&L[col * 64 + ((g ^ fsw(col)) << 3) + (h << 2)]) = p[c];
        }
        // ---- 4. single barrier per iteration ----
        __syncthreads();
        // ---- 5. MFMA: frag0 reused as A; 9 streamed B-frags per k2 ----
        #pragma unroll
        for (int k2 = 0; k2 < 2; ++k2) {
            const int kcq = k2 * 4 + quad;
            const int col0 = (w << 4) + m;
            const bf16x8 f0 = *(const bf16x8*)(&L[(col0 << 6) + ((kcq ^ fsw(col0)) << 3)]);
            #pragma unroll
            for (int j = 0; j < 9; ++j) {
                const int col = (((w + j) & 15) << 4) + m;
                const bf16x8 fj = *(const bf16x8*)(&L[(col << 6) + ((kcq ^ fsw(col)) << 3)]);
                acc[j] = __builtin_amdgcn_mfma_f32_16x16x32_bf16(f0, fj, acc[j], 0, 0, 0);
            }
        }
    };

    #pragma unroll
    for (int kk = 0; kk < CHUNK; kk += 2 * BK) {
        body(xvA, xvB, kk, 0);
        body(xvB, xvA, kk + BK, 1);
    }

    // ---- Z partial: plain store to this block's own slot (no atomic, no memset) ----
    __shared__ float red[16];
    if (lane == 0) red[w] = e_acc;
    __syncthreads();
    if (t == 0) {
        float z = 0.f;
        #pragma unroll
        for (int i = 0; i < 16; ++i) z += red[i];
        ws[b * 16 + ks] = z;
    }

    // ---- epilogue: 9 tiles -> gram[ks][b][slot=w*9+j][256] ----
    float* gb = gram + (size_t)(ks * NB + b) * 144 * 256;
    #pragma unroll
    for (int j = 0; j < 9; ++j) {
        float* tb = gb + (w * 9 + j) * 256 + quad * 64 + m;
        #pragma unroll
        for (int reg = 0; reg < 4; ++reg) tb[reg * 16] = acc[j][reg];
    }
}

// One wave per tile-slot: float4 reads of 16 partials, float4 direct write,
// mirror via padded LDS 16x16 transpose so it is float4-coalesced too.
// Mirror only j=1..7 (j=0 diagonal; j=8 pairs each written directly once).
__global__ __launch_bounds__(256) void k_reduce(const float* __restrict__ gram,
                                                const float* __restrict__ ws,
                                                float* __restrict__ out) {
    const int t = threadIdx.x;
    const int sg = t >> 6;                 // which of 4 slots in this block
    const int f = t & 63;                  // lane within the slot's wave
    const int gslot = blockIdx.x * 4 + sg; // 0..2303 = b*144 + slot
    const int b = gslot / 144;
    const int slot = gslot - b * 144;
    const int rt = slot / 9;
    const int j = slot - rt * 9;
    const int ct = (rt + j) & 15;
    const int er = f >> 2, ecq = f & 3;    // row 0..15, col-quad 0..3 in tile

    // sum 16 k-split partials, float4 per lane (16 independent loads in flight)
    const float* gp = gram + ((size_t)b * 144 + slot) * 256 + er * 16 + ecq * 4;
    float4 s = make_float4(0.f, 0.f, 0.f, 0.f);
    #pragma unroll
    for (int ks = 0; ks < KSPLIT; ++ks) {
        const float4 v = *(const float4*)(gp + (size_t)ks * (NB * 144 * 256));
        s.x += v.x; s.y += v.y; s.z += v.z; s.w += v.w;
    }

    // Z = sum of the 16 per-ks partials (uniform scalar loads, L2-hot)
    float z = 0.f;
    #pragma unroll
    for (int ks = 0; ks < KSPLIT; ++ks) z += ws[b * 16 + ks];
    const float zi = 1.0f / z;
    s.x *= zi; s.y *= zi; s.z *= zi; s.w *= zi;

    float* ob = out + (size_t)b * ND * ND;
    // direct write: rows of tile (rt,ct), fully coalesced float4
    *(float4*)(ob + (size_t)(rt * 16 + er) * ND + ct * 16 + ecq * 4) = s;

    // transpose through LDS (pad 16 -> 20 keeps 16B alignment, <=2-way banks)
    __shared__ float lt[4][16][20];
    lt[sg][ecq * 4 + 0][er] = s.x;
    lt[sg][ecq * 4 + 1][er] = s.y;
    lt[sg][ecq * 4 + 2][er] = s.z;
    lt[sg][ecq * 4 + 3][er] = s.w;
    __syncthreads();
    if (j >= 1 && j <= 7) {
        const float4 mv = *(const float4*)&lt[sg][er][ecq * 4];
        *(float4*)(ob + (size_t)(ct * 16 + er) * ND + rt * 16 + ecq * 4) = mv;
    }
}

extern "C" void kernel_launch(void* const* d_in, const int* in_sizes, int n_in,
                              void* d_out, int out_size, void* d_ws, size_t ws_size,
                              hipStream_t stream) {
    const float* x = (const float*)d_in[0];
    float* out = (float*)d_out;
    float* ws = (float*)d_ws;
    float* gram = ws + WS_G_OFF;

    k_gemm<<<dim3(KSPLIT, NB), 1024, 0, stream>>>(x, ws, gram);
    k_reduce<<<dim3(NB * 144 / 4), 256, 0, stream>>>(gram, ws, out);
}

// Round 3
// 209.426 us; speedup vs baseline: 1.0113x; 1.0113x over previous
//
#include <hip/hip_runtime.h>
#include <hip/hip_bf16.h>

#define NB 16
#define NL 8192
#define ND 256
#define KSPLIT 16
#define CHUNK (NL / KSPLIT)   // 512 rows per block
#define BK 64

#define WS_G_OFF 256          // floats; Z partial for (b,ks) at ws[b*16+ks]

typedef __bf16 bf16_t;
typedef __attribute__((ext_vector_type(4))) __bf16 bf16x4;
typedef __attribute__((ext_vector_type(8))) __bf16 bf16x8;
typedef __attribute__((ext_vector_type(4))) float floatx4;

// LDS: per col (0..255), 8 chunks of 8 bf16 (16B); physical chunk = kg ^ fsw(col).
__device__ __forceinline__ int fsw(int col) {
    return ((col >> 2) & 7) ^ ((col & 3) << 1);
}

// One block = 1024 threads = 16 waves, one (ks,b) chunk of 512 rows.
// Wave w computes row-tile w x col-tiles (w+j)&15, j=0..8 -> 144 slots
// (136 unique upper-tri + 8 d=8 pairs written once each side, no overlap).
// R3: R1's two-barrier single-LDS-buffer structure, but prefetch ISSUED AT
// THE TOP of each iteration into a ping-pong register set, so loads are in
// flight across butterfly+write+barrier+MFMA instead of just MFMA.
__global__ __launch_bounds__(1024, 4) void k_gemm(const float* __restrict__ x,
                                                  float* __restrict__ ws,
                                                  float* __restrict__ gram) {
    const int ks = blockIdx.x, b = blockIdx.y;
    const int t = threadIdx.x;
    const int lane = t & 63;
    const int w = __builtin_amdgcn_readfirstlane(t >> 6);   // wave id 0..15
    const int quad = lane >> 4, m = lane & 15;
    const int g = w >> 1, h = w & 1;   // 8-row chunk id, half within chunk

    __shared__ bf16_t lds[256 * 64];   // 32 KB, swizzled, single buffer

    const float* xb = x + (size_t)b * NL * ND;
    const int l0 = ks * CHUNK;

    floatx4 acc[9];
    #pragma unroll
    for (int j = 0; j < 9; ++j)
        #pragma unroll
        for (int r = 0; r < 4; ++r) acc[j][r] = 0.f;

    float e_acc = 0.f;
    float4 xvA[4], xvB[4];   // wave w stages rows kk+4w..+3; lane covers cols 4*lane..+3
    {
        const float* gp = xb + (size_t)(l0 + w * 4) * ND + lane * 4;
        #pragma unroll
        for (int j = 0; j < 4; ++j) xvA[j] = *(const float4*)(gp + (size_t)j * ND);
    }

    // butterfly + scale + swizzled LDS write from `cur`
    auto process = [&](const float4 (&cur)[4]) {
        float ss[4];
        #pragma unroll
        for (int j = 0; j < 4; ++j)
            ss[j] = cur[j].x * cur[j].x + cur[j].y * cur[j].y
                  + cur[j].z * cur[j].z + cur[j].w * cur[j].w;
        #pragma unroll
        for (int off = 32; off; off >>= 1) {
            #pragma unroll
            for (int j = 0; j < 4; ++j) ss[j] += __shfl_xor(ss[j], off, 64);
        }
        float s[4];
        #pragma unroll
        for (int j = 0; j < 4; ++j) {
            s[j] = __expf(0.5f * sqrtf(ss[j]));   // sqrt of softmax numerator
            e_acc += s[j] * s[j];
        }
        bf16x4 p[4];
        #pragma unroll
        for (int j = 0; j < 4; ++j) {
            const float* vf = (const float*)&cur[j];
            #pragma unroll
            for (int c = 0; c < 4; ++c) p[c][j] = (bf16_t)(vf[c] * s[j]);
        }
        #pragma unroll
        for (int c = 0; c < 4; ++c) {
            const int col = 4 * lane + c;
            *(bf16x4*)(&lds[col * 64 + ((g ^ fsw(col)) << 3) + (h << 2)]) = p[c];
        }
    };

    auto do_mfma = [&]() {
        #pragma unroll
        for (int k2 = 0; k2 < 2; ++k2) {
            const int kcq = k2 * 4 + quad;
            const int col0 = (w << 4) + m;
            const bf16x8 f0 = *(const bf16x8*)(&lds[(col0 << 6) + ((kcq ^ fsw(col0)) << 3)]);
            #pragma unroll
            for (int j = 0; j < 9; ++j) {
                const int col = (((w + j) & 15) << 4) + m;
                const bf16x8 fj = *(const bf16x8*)(&lds[(col << 6) + ((kcq ^ fsw(col)) << 3)]);
                acc[j] = __builtin_amdgcn_mfma_f32_16x16x32_bf16(f0, fj, acc[j], 0, 0, 0);
            }
        }
    };

    for (int kk = 0; kk < CHUNK; kk += 2 * BK) {
        // ---------- half A: consume xvA, prefetch kk+BK into xvB ----------
        if (kk) __syncthreads();          // prev MFMA's LDS reads done
        {   // kk+BK < CHUNK always holds here
            const float* gp = xb + (size_t)(l0 + kk + BK + w * 4) * ND + lane * 4;
            #pragma unroll
            for (int j = 0; j < 4; ++j) xvB[j] = *(const float4*)(gp + (size_t)j * ND);
        }
        process(xvA);
        __syncthreads();
        do_mfma();

        // ---------- half B: consume xvB, prefetch kk+2*BK into xvA ----------
        __syncthreads();                  // this half's LDS reads done
        if (kk + 2 * BK < CHUNK) {
            const float* gp = xb + (size_t)(l0 + kk + 2 * BK + w * 4) * ND + lane * 4;
            #pragma unroll
            for (int j = 0; j < 4; ++j) xvA[j] = *(const float4*)(gp + (size_t)j * ND);
        }
        process(xvB);
        __syncthreads();
        do_mfma();
    }

    // ---- Z partial: plain store to this block's own slot (no atomic, no memset) ----
    __shared__ float red[16];
    if (lane == 0) red[w] = e_acc;
    __syncthreads();
    if (t == 0) {
        float z = 0.f;
        #pragma unroll
        for (int i = 0; i < 16; ++i) z += red[i];
        ws[b * 16 + ks] = z;
    }

    // ---- epilogue: 9 tiles -> gram[ks][b][slot=w*9+j][256] ----
    float* gb = gram + (size_t)(ks * NB + b) * 144 * 256;
    #pragma unroll
    for (int j = 0; j < 9; ++j) {
        float* tb = gb + (w * 9 + j) * 256 + quad * 64 + m;
        #pragma unroll
        for (int reg = 0; reg < 4; ++reg) tb[reg * 16] = acc[j][reg];
    }
}

// One wave per tile-slot: float4 reads of 16 partials, float4 direct write,
// mirror via padded LDS 16x16 transpose so it is float4-coalesced too.
// Mirror only j=1..7 (j=0 diagonal; j=8 pairs each written directly once).
__global__ __launch_bounds__(256) void k_reduce(const float* __restrict__ gram,
                                                const float* __restrict__ ws,
                                                float* __restrict__ out) {
    const int t = threadIdx.x;
    const int sg = t >> 6;                 // which of 4 slots in this block
    const int f = t & 63;                  // lane within the slot's wave
    const int gslot = blockIdx.x * 4 + sg; // 0..2303 = b*144 + slot
    const int b = gslot / 144;
    const int slot = gslot - b * 144;
    const int rt = slot / 9;
    const int j = slot - rt * 9;
    const int ct = (rt + j) & 15;
    const int er = f >> 2, ecq = f & 3;    // row 0..15, col-quad 0..3 in tile

    // sum 16 k-split partials, float4 per lane (16 independent loads in flight)
    const float* gp = gram + ((size_t)b * 144 + slot) * 256 + er * 16 + ecq * 4;
    float4 s = make_float4(0.f, 0.f, 0.f, 0.f);
    #pragma unroll
    for (int ks = 0; ks < KSPLIT; ++ks) {
        const float4 v = *(const float4*)(gp + (size_t)ks * (NB * 144 * 256));
        s.x += v.x; s.y += v.y; s.z += v.z; s.w += v.w;
    }

    // Z = sum of the 16 per-ks partials (uniform scalar loads, L2-hot)
    float z = 0.f;
    #pragma unroll
    for (int ks = 0; ks < KSPLIT; ++ks) z += ws[b * 16 + ks];
    const float zi = 1.0f / z;
    s.x *= zi; s.y *= zi; s.z *= zi; s.w *= zi;

    float* ob = out + (size_t)b * ND * ND;
    // direct write: rows of tile (rt,ct), fully coalesced float4
    *(float4*)(ob + (size_t)(rt * 16 + er) * ND + ct * 16 + ecq * 4) = s;

    // transpose through LDS (pad 16 -> 20 keeps 16B alignment, <=2-way banks)
    __shared__ float lt[4][16][20];
    lt[sg][ecq * 4 + 0][er] = s.x;
    lt[sg][ecq * 4 + 1][er] = s.y;
    lt[sg][ecq * 4 + 2][er] = s.z;
    lt[sg][ecq * 4 + 3][er] = s.w;
    __syncthreads();
    if (j >= 1 && j <= 7) {
        const float4 mv = *(const float4*)&lt[sg][er][ecq * 4];
        *(float4*)(ob + (size_t)(ct * 16 + er) * ND + rt * 16 + ecq * 4) = mv;
    }
}

extern "C" void kernel_launch(void* const* d_in, const int* in_sizes, int n_in,
                              void* d_out, int out_size, void* d_ws, size_t ws_size,
                              hipStream_t stream) {
    const float* x = (const float*)d_in[0];
    float* out = (float*)d_out;
    float* ws = (float*)d_ws;
    float* gram = ws + WS_G_OFF;

    k_gemm<<<dim3(KSPLIT, NB), 1024, 0, stream>>>(x, ws, gram);
    k_reduce<<<dim3(NB * 144 / 4), 256, 0, stream>>>(gram, ws, out);
}

// Round 4
// 205.242 us; speedup vs baseline: 1.0320x; 1.0204x over previous
//
#include <hip/hip_runtime.h>
#include <hip/hip_bf16.h>

#define NB 16
#define NL 8192
#define ND 256
#define KSPLIT 16
#define CHUNK (NL / KSPLIT)   // 512 rows per block
#define BK 64

#define WS_G_OFF 256          // floats; Z partial for (b,ks) at ws[b*16+ks]

typedef __bf16 bf16_t;
typedef __attribute__((ext_vector_type(4))) __bf16 bf16x4;
typedef __attribute__((ext_vector_type(8))) __bf16 bf16x8;
typedef __attribute__((ext_vector_type(4))) float floatx4;

// LDS: per col (0..255), 8 chunks of 8 bf16 (16B); physical chunk = kg ^ fsw(col).
__device__ __forceinline__ int fsw(int col) {
    return ((col >> 2) & 7) ^ ((col & 3) << 1);
}

// Full-wave (64-lane) sum on the VALU pipe: DPP row_shr chain + row broadcasts,
// result broadcast to all lanes via readlane (SGPR). Frees the DS pipe of the
// 24 ds_swizzle/wave the old __shfl_xor butterfly cost.
__device__ __forceinline__ float wave_sum64(float v) {
#define DPPADD(ctrl)                                                              \
    {                                                                             \
        int s_ = __builtin_amdgcn_update_dpp(0, __builtin_bit_cast(int, v),       \
                                             ctrl, 0xF, 0xF, true);               \
        v += __builtin_bit_cast(float, s_);                                       \
    }
    DPPADD(0x111)  // row_shr:1
    DPPADD(0x112)  // row_shr:2
    DPPADD(0x114)  // row_shr:4
    DPPADD(0x118)  // row_shr:8  -> lane15 of each row16 = row sum
    DPPADD(0x142)  // row_bcast15 -> lane31 = rows0+1, lane63 = rows2+3
    DPPADD(0x143)  // row_bcast31 -> lane63 = total
#undef DPPADD
    return __builtin_bit_cast(float,
        __builtin_amdgcn_readlane(__builtin_bit_cast(int, v), 63));
}

// One block = 1024 threads = 16 waves, one (ks,b) chunk of 512 rows.
// 3x3 tile blocking via cyclic difference cover: wave w owns row-tiles
// {w,w+1,w+2} x col-tiles {w+2,w+5,w+8} (mod 16). Differences 2+3j-i cover
// {0..8} exactly once -> 144 slots = 136 unique pairs + 8 d=8 dups, identical
// coverage to the old 1x9 band but 6 frag reads per 9 MFMA instead of 10.
__global__ __launch_bounds__(1024, 4) void k_gemm(const float* __restrict__ x,
                                                  float* __restrict__ ws,
                                                  float* __restrict__ gram) {
    const int ks = blockIdx.x, b = blockIdx.y;
    const int t = threadIdx.x;
    const int lane = t & 63;
    const int w = __builtin_amdgcn_readfirstlane(t >> 6);   // wave id 0..15
    const int quad = lane >> 4, m = lane & 15;
    const int g = w >> 1, h = w & 1;   // 8-row chunk id, half within chunk

    __shared__ bf16_t lds[256 * 64];   // 32 KB, swizzled, single buffer

    const float* xb = x + (size_t)b * NL * ND;
    const int l0 = ks * CHUNK;

    floatx4 acc[9];
    #pragma unroll
    for (int j = 0; j < 9; ++j)
        #pragma unroll
        for (int r = 0; r < 4; ++r) acc[j][r] = 0.f;

    float e_acc = 0.f;
    float4 xv[4];   // wave w stages rows kk+4w..+3; lane covers cols 4*lane..+3
    {
        const float* gp = xb + (size_t)(l0 + w * 4) * ND + lane * 4;
        #pragma unroll
        for (int j = 0; j < 4; ++j) xv[j] = *(const float4*)(gp + (size_t)j * ND);
    }

    for (int kk = 0; kk < CHUNK; kk += BK) {
        if (kk) __syncthreads();   // prev iter's LDS reads done
        // ---- norm reduce (VALU/DPP) + scale + swizzled LDS write ----
        {
            float s[4];
            #pragma unroll
            for (int j = 0; j < 4; ++j) {
                float ssl = xv[j].x * xv[j].x + xv[j].y * xv[j].y
                          + xv[j].z * xv[j].z + xv[j].w * xv[j].w;
                const float tot = wave_sum64(ssl);
                s[j] = __expf(0.5f * sqrtf(tot));   // sqrt of softmax numerator
                e_acc += s[j] * s[j];
            }
            bf16x4 p[4];
            #pragma unroll
            for (int j = 0; j < 4; ++j) {
                const float* vf = (const float*)&xv[j];
                #pragma unroll
                for (int c = 0; c < 4; ++c) p[c][j] = (bf16_t)(vf[c] * s[j]);
            }
            #pragma unroll
            for (int c = 0; c < 4; ++c) {
                const int col = 4 * lane + c;
                *(bf16x4*)(&lds[col * 64 + ((g ^ fsw(col)) << 3) + (h << 2)]) = p[c];
            }
        }
        __syncthreads();
        // ---- prefetch next iter (lands during MFMA below) ----
        if (kk + BK < CHUNK) {
            const float* gp = xb + (size_t)(l0 + kk + BK + w * 4) * ND + lane * 4;
            #pragma unroll
            for (int j = 0; j < 4; ++j) xv[j] = *(const float4*)(gp + (size_t)j * ND);
        }
        // ---- MFMA: 3 A-frags x 3 B-frags per k2 (6 reads / 9 MFMA) ----
        #pragma unroll
        for (int k2 = 0; k2 < 2; ++k2) {
            const int kcq = k2 * 4 + quad;
            bf16x8 fA[3], fB[3];
            #pragma unroll
            for (int i = 0; i < 3; ++i) {
                const int colA = (((w + i) & 15) << 4) + m;
                fA[i] = *(const bf16x8*)(&lds[(colA << 6) + ((kcq ^ fsw(colA)) << 3)]);
                const int colB = (((w + 2 + 3 * i) & 15) << 4) + m;
                fB[i] = *(const bf16x8*)(&lds[(colB << 6) + ((kcq ^ fsw(colB)) << 3)]);
            }
            #pragma unroll
            for (int i = 0; i < 3; ++i)
                #pragma unroll
                for (int j = 0; j < 3; ++j)
                    acc[i * 3 + j] = __builtin_amdgcn_mfma_f32_16x16x32_bf16(
                        fA[i], fB[j], acc[i * 3 + j], 0, 0, 0);
        }
    }

    // ---- Z partial: plain store to this block's own slot (no atomic, no memset) ----
    __shared__ float red[16];
    if (lane == 0) red[w] = e_acc;
    __syncthreads();
    if (t == 0) {
        float z = 0.f;
        #pragma unroll
        for (int i = 0; i < 16; ++i) z += red[i];
        ws[b * 16 + ks] = z;
    }

    // ---- epilogue: 9 tiles -> gram[ks][b][slot=w*9+idx][256] ----
    float* gb = gram + (size_t)(ks * NB + b) * 144 * 256;
    #pragma unroll
    for (int j = 0; j < 9; ++j) {
        float* tb = gb + (w * 9 + j) * 256 + quad * 64 + m;
        #pragma unroll
        for (int reg = 0; reg < 4; ++reg) tb[reg * 16] = acc[j][reg];
    }
}

// One wave per tile-slot: float4 reads of 16 partials, float4 direct write,
// mirror via padded LDS 16x16 transpose so it is float4-coalesced too.
// slot = w*9 + i*3 + j -> rt=(w+i)&15, d=2+3j-i in {0..8}, ct=(rt+d)&15.
// Mirror only d=1..7 (d=0 diagonal; d=8 pairs each written directly once).
__global__ __launch_bounds__(256) void k_reduce(const float* __restrict__ gram,
                                                const float* __restrict__ ws,
                                                float* __restrict__ out) {
    const int t = threadIdx.x;
    const int sg = t >> 6;                 // which of 4 slots in this block
    const int f = t & 63;                  // lane within the slot's wave
    const int gslot = blockIdx.x * 4 + sg; // 0..2303 = b*144 + slot
    const int b = gslot / 144;
    const int slot = gslot - b * 144;
    const int wv = slot / 9;
    const int r = slot - wv * 9;
    const int i = r / 3, jj = r - i * 3;
    const int rt = (wv + i) & 15;
    const int d = 2 + 3 * jj - i;          // 0..8
    const int ct = (rt + d) & 15;
    const int er = f >> 2, ecq = f & 3;    // row 0..15, col-quad 0..3 in tile

    // sum 16 k-split partials, float4 per lane (16 independent loads in flight)
    const float* gp = gram + ((size_t)b * 144 + slot) * 256 + er * 16 + ecq * 4;
    float4 s = make_float4(0.f, 0.f, 0.f, 0.f);
    #pragma unroll
    for (int ks = 0; ks < KSPLIT; ++ks) {
        const float4 v = *(const float4*)(gp + (size_t)ks * (NB * 144 * 256));
        s.x += v.x; s.y += v.y; s.z += v.z; s.w += v.w;
    }

    // Z = sum of the 16 per-ks partials (uniform scalar loads, L2-hot)
    float z = 0.f;
    #pragma unroll
    for (int ks = 0; ks < KSPLIT; ++ks) z += ws[b * 16 + ks];
    const float zi = 1.0f / z;
    s.x *= zi; s.y *= zi; s.z *= zi; s.w *= zi;

    float* ob = out + (size_t)b * ND * ND;
    // direct write: rows of tile (rt,ct), fully coalesced float4
    *(float4*)(ob + (size_t)(rt * 16 + er) * ND + ct * 16 + ecq * 4) = s;

    // transpose through LDS (pad 16 -> 20 keeps 16B alignment, <=2-way banks)
    __shared__ float lt[4][16][20];
    lt[sg][ecq * 4 + 0][er] = s.x;
    lt[sg][ecq * 4 + 1][er] = s.y;
    lt[sg][ecq * 4 + 2][er] = s.z;
    lt[sg][ecq * 4 + 3][er] = s.w;
    __syncthreads();
    if (d >= 1 && d <= 7) {
        const float4 mv = *(const float4*)&lt[sg][er][ecq * 4];
        *(float4*)(ob + (size_t)(ct * 16 + er) * ND + rt * 16 + ecq * 4) = mv;
    }
}

extern "C" void kernel_launch(void* const* d_in, const int* in_sizes, int n_in,
                              void* d_out, int out_size, void* d_ws, size_t ws_size,
                              hipStream_t stream) {
    const float* x = (const float*)d_in[0];
    float* out = (float*)d_out;
    float* ws = (float*)d_ws;
    float* gram = ws + WS_G_OFF;

    k_gemm<<<dim3(KSPLIT, NB), 1024, 0, stream>>>(x, ws, gram);
    k_reduce<<<dim3(NB * 144 / 4), 256, 0, stream>>>(gram, ws, out);
}